// Round 24
// baseline (25.841 us; speedup 1.0000x reference)
//
#include <hip/hip_runtime.h>
#include <hip/hip_bf16.h>

// AWQ 4-bit linear: out[32,11008] = x[32,4096] @ ((q - z)*s) + bias
// Round 24: SINGLE-VARIABLE on the R22/R23 winner (25.7us): s_setprio(1)
// around the 8-MFMA cluster (T5). Our main loop is barrier-free with
// independent waves at different phases -- the attn-like regime where
// setprio measured +4-7% (m191); it was null only for barrier-lockstep
// GEMM waves (m190). Everything else byte-identical: 688 blk,
// 128col x 2kchunk blocks, fp16 perm-dequant, q-hoist, software pipeline,
// rotated-slot LDS, in-block k-pair sum, 8 bf16 nt-slabs + reduce.

#define IN_F   4096
#define OUT_F  11008
#define WCOLS  1376
#define NCOLB  86                 // 128-col regions
#define NKC    8                  // slab k-regions (2 kchunks each)
#define CHUNK  256                // k per wave
#define NTILE  (CHUNK/32)         // 8
#define NBLK   (NCOLB*NKC)        // 688 = 8*86
#define MROWS  32
#define SLAB   (MROWS*OUT_F)      // elements per k-partial slab (352256)

typedef __attribute__((ext_vector_type(2))) _Float16 half2v;
typedef __attribute__((ext_vector_type(8))) _Float16 half8v;
typedef __attribute__((ext_vector_type(4))) unsigned short ushort4v;
typedef __attribute__((ext_vector_type(4))) float  f32x4;
typedef __attribute__((ext_vector_type(4))) int    int4v;

__device__ __forceinline__ unsigned short f2bfu(float f) {
  return __builtin_bit_cast(unsigned short, (__bf16)f);
}
__device__ __forceinline__ float bf2f(unsigned short u) {
  return __builtin_bit_cast(float, ((unsigned int)u) << 16);
}
__device__ __forceinline__ half2v splat_h(float f) {
  unsigned short b = __builtin_bit_cast(unsigned short, (_Float16)f);
  unsigned int u = (unsigned int)b | ((unsigned int)b << 16);
  return __builtin_bit_cast(half2v, u);
}
__device__ __forceinline__ f32x4 mfma16h(half8v a, half8v b, f32x4 c) {
  return __builtin_amdgcn_mfma_f32_16x16x32_f16(a, b, c, 0, 0, 0);
}

__global__ void awq_init(const float* __restrict__ bias, float* __restrict__ out) {
  int o = blockIdx.x * 256 + threadIdx.x;
  out[blockIdx.y * OUT_F + o] = bias[o];
}

__global__ __launch_bounds__(256) void awq_reduce(
    const unsigned short* __restrict__ ws, const float* __restrict__ bias,
    float* __restrict__ out)
{
  const int i = blockIdx.x * 256 + threadIdx.x;    // 4-col id, 88064 total
  f32x4 s = *(const f32x4*)(bias + (i % (OUT_F / 4)) * 4);
  const ushort4v* w4 = (const ushort4v*)ws;
  #pragma unroll
  for (int k = 0; k < NKC; ++k) {
    ushort4v v = __builtin_nontemporal_load(&w4[k * (SLAB / 4) + i]);
    #pragma unroll
    for (int j = 0; j < 4; ++j) s[j] += bf2f(v[j]);
  }
  ((f32x4*)out)[i] = s;
}

template<bool TOWS>
__global__ __launch_bounds__(256, 3) void awq_main(
    const float* __restrict__ x,
    const int* __restrict__ qw, const int* __restrict__ qz,
    const float* __restrict__ sc, void* __restrict__ outp)
{
  // Per-wave, per-half private staging: [buf][wave][half][512 dw] = 32 KB.
  // lds[0] (16 KB) doubles as the end-of-kernel acc-exchange buffer.
  __shared__ int lds[2][4][2][512];

  const int tid  = threadIdx.x;
  const int w    = tid >> 6;           // wave 0..3
  const int wk   = w & 1;              // 64-col stripe within 128-col region
  const int kh   = w >> 1;             // k-half 0/1
  const int lane = tid & 63;
  const int q4   = lane >> 4;          // MFMA k-octet
  const int cl   = lane & 15;          // MFMA col-in-frag
  const int ww   = lane & 3;           // dequant: word -> cols 8ww..8ww+7
  const int kp2  = lane >> 2;          // dequant: k-pair 0..15
  const int kps  = kp2 ^ (ww << 2);    // swizzled k-pair slot (verified)

  // Bijective XCD swizzle (688 = 8*86)
  const int b  = blockIdx.x;
  const int L  = (b & 7) * (NBLK / 8) + (b >> 3);
  const int colb = L % NCOLB;
  const int kc   = L / NCOLB;          // slab k-region 0..7

  const int kchunk = kc * 2 + kh;      // 0..15
  const int cb  = colb * 128;          // first output column of region
  const int wcb = colb * 16;           // first packed word of region
  const int K0  = kchunk * CHUNK;
  const int g0  = kchunk * (CHUNK / 128);   // 2 groups per chunk
  const int cw  = cb + wk * 64;        // wave's first column
  const int wqw = wcb + wk * 8;        // wave's first packed word

  // group scale/zero per half: raw staging -> fp16 splat pairs
  f32x4 sra[2], srb[2]; int zrw[2];
  half2v nz[2][8], ss[2][8];
  auto load_group_raw = [&](int g) {
    #pragma unroll
    for (int h = 0; h < 2; ++h) {
      sra[h] = *(const f32x4*)(sc + g * OUT_F + cw + h * 32 + ww * 8);
      srb[h] = *(const f32x4*)(sc + g * OUT_F + cw + h * 32 + ww * 8 + 4);
      zrw[h] = qz[g * WCOLS + wqw + h * 4 + ww];
    }
  };
  auto conv_group = [&]() {
    #pragma unroll
    for (int h = 0; h < 2; ++h) {
      #pragma unroll
      for (int l = 0; l < 8; ++l) {
        const int sh = 4 * (l >> 1) + 16 * (l & 1);   // shift = 4*REV[l]
        const int zi = (zrw[h] >> sh) & 15;
        nz[h][l] = splat_h(-(float)(1024 + zi));
        ss[h][l] = splat_h((l < 4) ? sra[h][l] : srb[h][l - 4]);
      }
    }
  };
  auto load_a = [&](int t, int mf) -> half8v {
    const int m = cl + 16 * mf;
    const int k = K0 + t * 32 + q4 * 8;
    const f32x4* xp = (const f32x4*)(x + m * IN_F + k);
    const f32x4 lo = xp[0], hi = xp[1];
    int4v wd;
    wd[0] = __builtin_bit_cast(int, __builtin_amdgcn_cvt_pkrtz(lo[0], lo[1]));
    wd[1] = __builtin_bit_cast(int, __builtin_amdgcn_cvt_pkrtz(lo[2], lo[3]));
    wd[2] = __builtin_bit_cast(int, __builtin_amdgcn_cvt_pkrtz(hi[0], hi[1]));
    wd[3] = __builtin_bit_cast(int, __builtin_amdgcn_cvt_pkrtz(hi[2], hi[3]));
    return __builtin_bit_cast(half8v, wd);
  };
  // read col c, k=8q4..8q4+7: slot s=4(c&7)+(c>>3), quads at 4*(q4^(c>>3))
  // contiguous since (4q4+m)^(4w') = 4(q4^w')+m.
  auto read_b = [&](int p, int h, int c) -> half8v {
    const int s = ((c & 7) << 2) | (c >> 3);
    const int idx = s * 16 + 4 * (q4 ^ (c >> 3));
    return __builtin_bit_cast(half8v, *(const int4v*)&lds[p][w][h][idx]);
  };

  // ---- prologue: group-0 raws, ALL q-loads (8 tiles x 2 halves) to regs.
  load_group_raw(g0);
  int qa[NTILE][2], qb[NTILE][2];
  #pragma unroll
  for (int t = 0; t < NTILE; ++t) {
    #pragma unroll
    for (int h = 0; h < 2; ++h) {
      const int r = (K0 + t * 32 + 2 * kp2) * WCOLS + wqw + h * 4 + ww;
      qa[t][h] = qw[r];
      qb[t][h] = qw[r + WCOLS];
    }
  }
  conv_group();
  f32x4 acc[2][2][2] = {};   // [mf][h][cfrag]

  // fp16 perm-dequant + LDS-write for tile t. Store col c=8ww+l at slot
  // l*4+ww (bank = 16(ww&1)+kps -> 2-way, free), quad kps.
  auto dq_write = [&](int t) {
    const int p = t & 1;
    #pragma unroll
    for (int h = 0; h < 2; ++h) {
      const int q0 = qa[t][h], q1 = qb[t][h];
      const int h0 = (int)((unsigned)q0 >> 4);
      const int h1 = (int)((unsigned)q1 >> 4);
      #pragma unroll
      for (int l = 0; l < 8; ++l) {
        const int pb = 2 * (l & 1) + (l >> 2);             // source byte
        const unsigned sel = (unsigned)(4 + pb) | ((unsigned)(4 + pb) << 8)
                           | ((unsigned)pb << 16) | ((unsigned)pb << 24);
        const int x0 = ((l >> 1) & 1) ? h0 : q0;
        const int x1 = ((l >> 1) & 1) ? h1 : q1;
        unsigned P = __builtin_amdgcn_perm((unsigned)x0, (unsigned)x1, sel);
        unsigned W = (P & 0x000F000Fu) | 0x64006400u;      // fp16: 1024+n
        half2v wh = (__builtin_bit_cast(half2v, W) + nz[h][l]) * ss[h][l];
        lds[p][w][h][(l * 4 + ww) * 16 + kps] = __builtin_bit_cast(int, wh);
      }
    }
  };

  // ---- pipelined main loop: write(t) while consuming (t-1)
  dq_write(0);
  half8v a0c = load_a(0, 0), a1c = load_a(0, 1);

  #pragma unroll
  for (int t = 1; t < NTILE; ++t) {
    const int pm = (t - 1) & 1;
    half8v bf00 = read_b(pm, 0, cl), bf01 = read_b(pm, 0, cl + 16);
    half8v bf10 = read_b(pm, 1, cl), bf11 = read_b(pm, 1, cl + 16);
    half8v a0n = load_a(t, 0), a1n = load_a(t, 1);
    if (t == 2) load_group_raw(g0 + 1);   // raws 2 tiles early
    if (t == 4) conv_group();             // group 1 live for tiles 4..7

    dq_write(t);                          // VALU hides the reads above

    __builtin_amdgcn_s_setprio(1);        // favor this wave through MFMAs
    acc[0][0][0] = mfma16h(a0c, bf00, acc[0][0][0]);
    acc[0][0][1] = mfma16h(a0c, bf01, acc[0][0][1]);
    acc[1][0][0] = mfma16h(a1c, bf00, acc[1][0][0]);
    acc[1][0][1] = mfma16h(a1c, bf01, acc[1][0][1]);
    acc[0][1][0] = mfma16h(a0c, bf10, acc[0][1][0]);
    acc[0][1][1] = mfma16h(a0c, bf11, acc[0][1][1]);
    acc[1][1][0] = mfma16h(a1c, bf10, acc[1][1][0]);
    acc[1][1][1] = mfma16h(a1c, bf11, acc[1][1][1]);
    __builtin_amdgcn_s_setprio(0);

    a0c = a0n; a1c = a1n;
  }

  // ---- final tile (reads from lds[1] only: pm = 7&1 = 1)
  {
    const int pm = (NTILE - 1) & 1;
    half8v bf00 = read_b(pm, 0, cl), bf01 = read_b(pm, 0, cl + 16);
    half8v bf10 = read_b(pm, 1, cl), bf11 = read_b(pm, 1, cl + 16);
    __builtin_amdgcn_s_setprio(1);
    acc[0][0][0] = mfma16h(a0c, bf00, acc[0][0][0]);
    acc[0][0][1] = mfma16h(a0c, bf01, acc[0][0][1]);
    acc[1][0][0] = mfma16h(a1c, bf00, acc[1][0][0]);
    acc[1][0][1] = mfma16h(a1c, bf01, acc[1][0][1]);
    acc[0][1][0] = mfma16h(a0c, bf10, acc[0][1][0]);
    acc[0][1][1] = mfma16h(a0c, bf11, acc[0][1][1]);
    acc[1][1][0] = mfma16h(a1c, bf10, acc[1][1][0]);
    acc[1][1][1] = mfma16h(a1c, bf11, acc[1][1][1]);
    __builtin_amdgcn_s_setprio(0);
  }

  // ---- output epilogue
  const int r0 = q4 * 4;
  if constexpr (TOWS) {
    // in-block k-pair sum through lds[0] (idx-major: conflict-free,
    // no overlap with lds[1], which held the final tile)
    float* xch = (float*)&lds[0][0][0][0];   // 4096 floats = 16 KB
    const int base = wk * 64 + lane;         // 0..127
    __syncthreads();                         // all waves past main loop
    if (kh == 1) {
      #pragma unroll
      for (int mf = 0; mf < 2; ++mf)
        #pragma unroll
        for (int h = 0; h < 2; ++h)
          #pragma unroll
          for (int cf = 0; cf < 2; ++cf)
            #pragma unroll
            for (int i = 0; i < 4; ++i) {
              const int e = (((mf * 2 + h) * 2 + cf) * 4 + i);
              xch[e * 128 + base] = acc[mf][h][cf][i];
            }
    }
    __syncthreads();
    if (kh == 0) {
      unsigned short* wsp = (unsigned short*)outp + kc * SLAB;
      #pragma unroll
      for (int mf = 0; mf < 2; ++mf)
        #pragma unroll
        for (int h = 0; h < 2; ++h)
          #pragma unroll
          for (int cf = 0; cf < 2; ++cf)
            #pragma unroll
            for (int i = 0; i < 4; ++i) {
              const int e = (((mf * 2 + h) * 2 + cf) * 4 + i);
              const float sum = acc[mf][h][cf][i] + xch[e * 128 + base];
              const int row = mf * 16 + r0 + i;
              const int c0  = cw + h * 32 + cl + cf * 16;
              __builtin_nontemporal_store(f2bfu(sum), wsp + row * OUT_F + c0);
            }
    }
  } else {
    // fallback: fp32 atomics onto bias-initialized out
    float* op = (float*)outp;
    #pragma unroll
    for (int mf = 0; mf < 2; ++mf) {
      #pragma unroll
      for (int h = 0; h < 2; ++h) {
        #pragma unroll
        for (int i = 0; i < 4; ++i) {
          const int row = mf * 16 + r0 + i;
          const int c0  = cw + h * 32 + cl;
          atomicAdd(op + row * OUT_F + c0,      acc[mf][h][0][i]);
          atomicAdd(op + row * OUT_F + c0 + 16, acc[mf][h][1][i]);
        }
      }
    }
  }
}

extern "C" void kernel_launch(void* const* d_in, const int* in_sizes, int n_in,
                              void* d_out, int out_size, void* d_ws, size_t ws_size,
                              hipStream_t stream) {
  const float* x    = (const float*)d_in[0];
  const int*   qwp  = (const int*)d_in[1];
  const int*   qzp  = (const int*)d_in[2];
  const float* scp  = (const float*)d_in[3];
  const float* bias = (const float*)d_in[4];
  float* out = (float*)d_out;

  const size_t ws_slabs = (size_t)NKC * SLAB * 2;   // 5.6 MB (bf16)

  if (ws_size >= ws_slabs) {
    unsigned short* ws = (unsigned short*)d_ws;
    awq_main<true><<<NBLK, 256, 0, stream>>>(x, qwp, qzp, scp, ws);
    awq_reduce<<<SLAB / 4 / 256, 256, 0, stream>>>(ws, bias, out);
  } else {
    awq_init<<<dim3(43, 32), 256, 0, stream>>>(bias, out);
    awq_main<false><<<NBLK, 256, 0, stream>>>(x, qwp, qzp, scp, out);
  }
}

// Round 25
// 24.061 us; speedup vs baseline: 1.0739x; 1.0739x over previous
//
#include <hip/hip_runtime.h>
#include <hip/hip_bf16.h>

// AWQ 4-bit linear: out[32,11008] = x[32,4096] @ ((q - z)*s) + bias
// Round 25: TA/L1 LINE-LOOKUP model (retrodicts R16's -4.3us: lookups/CU
// delta = 4.6us at 1cy/line; explains all-neutral rounds: lookup count
// invariant; TA stalls invisible in VALU/MFMA/HBM counters).
// Change: A-path staged as xb2[k-octet][m][8] fp16 (256 KB in ws, written
// by tiny xconv2). load_a = ONE 16B/lane fully-coalesced instruction
// (16 lines/KB, the optimum) -> a-lookups 1024 -> 256 per wave
// (-8.3k cy/CU ~ -3.4us) vs +1 small launch. Base = R23 (no setprio);
// q-path, dequant, pipeline, exchange, slabs, reduce unchanged.

#define IN_F   4096
#define OUT_F  11008
#define WCOLS  1376
#define NCOLB  86                 // 128-col regions
#define NKC    8                  // slab k-regions (2 kchunks each)
#define CHUNK  256                // k per wave
#define NTILE  (CHUNK/32)         // 8
#define NBLK   (NCOLB*NKC)        // 688 = 8*86
#define MROWS  32
#define SLAB   (MROWS*OUT_F)      // elements per k-partial slab (352256)

typedef __attribute__((ext_vector_type(2))) _Float16 half2v;
typedef __attribute__((ext_vector_type(8))) _Float16 half8v;
typedef __attribute__((ext_vector_type(4))) unsigned short ushort4v;
typedef __attribute__((ext_vector_type(4))) float  f32x4;
typedef __attribute__((ext_vector_type(4))) int    int4v;

__device__ __forceinline__ unsigned short f2bfu(float f) {
  return __builtin_bit_cast(unsigned short, (__bf16)f);
}
__device__ __forceinline__ float bf2f(unsigned short u) {
  return __builtin_bit_cast(float, ((unsigned int)u) << 16);
}
__device__ __forceinline__ half2v splat_h(float f) {
  unsigned short b = __builtin_bit_cast(unsigned short, (_Float16)f);
  unsigned int u = (unsigned int)b | ((unsigned int)b << 16);
  return __builtin_bit_cast(half2v, u);
}
__device__ __forceinline__ f32x4 mfma16h(half8v a, half8v b, f32x4 c) {
  return __builtin_amdgcn_mfma_f32_16x16x32_f16(a, b, c, 0, 0, 0);
}

__global__ void awq_init(const float* __restrict__ bias, float* __restrict__ out) {
  int o = blockIdx.x * 256 + threadIdx.x;
  out[blockIdx.y * OUT_F + o] = bias[o];
}

// x[32][4096] f32 -> xb2[ko 0..511][m 0..31][8] fp16 (fragment-major).
// Writes fully coalesced (consecutive g -> consecutive 16B).
__global__ __launch_bounds__(256) void xconv2(
    const float* __restrict__ x, _Float16* __restrict__ xb2)
{
  const int g  = blockIdx.x * 256 + threadIdx.x;   // 64 blocks -> 16384
  const int m  = g & 31;
  const int ko = g >> 5;
  const f32x4* xp = (const f32x4*)(x + m * IN_F + ko * 8);
  const f32x4 lo = xp[0], hi = xp[1];
  int4v wd;
  wd[0] = __builtin_bit_cast(int, __builtin_amdgcn_cvt_pkrtz(lo[0], lo[1]));
  wd[1] = __builtin_bit_cast(int, __builtin_amdgcn_cvt_pkrtz(lo[2], lo[3]));
  wd[2] = __builtin_bit_cast(int, __builtin_amdgcn_cvt_pkrtz(hi[0], hi[1]));
  wd[3] = __builtin_bit_cast(int, __builtin_amdgcn_cvt_pkrtz(hi[2], hi[3]));
  ((int4v*)xb2)[g] = wd;
}

__global__ __launch_bounds__(256) void awq_reduce(
    const unsigned short* __restrict__ ws, const float* __restrict__ bias,
    float* __restrict__ out)
{
  const int i = blockIdx.x * 256 + threadIdx.x;    // 4-col id, 88064 total
  f32x4 s = *(const f32x4*)(bias + (i % (OUT_F / 4)) * 4);
  const ushort4v* w4 = (const ushort4v*)ws;
  #pragma unroll
  for (int k = 0; k < NKC; ++k) {
    ushort4v v = __builtin_nontemporal_load(&w4[k * (SLAB / 4) + i]);
    #pragma unroll
    for (int j = 0; j < 4; ++j) s[j] += bf2f(v[j]);
  }
  ((f32x4*)out)[i] = s;
}

template<bool TOWS>
__global__ __launch_bounds__(256, 3) void awq_main(
    const float* __restrict__ x, const _Float16* __restrict__ xb2,
    const int* __restrict__ qw, const int* __restrict__ qz,
    const float* __restrict__ sc, void* __restrict__ outp)
{
  // Per-wave, per-half private staging: [buf][wave][half][512 dw] = 32 KB.
  // lds[0] (16 KB) doubles as the end-of-kernel acc-exchange buffer.
  __shared__ int lds[2][4][2][512];

  const int tid  = threadIdx.x;
  const int w    = tid >> 6;           // wave 0..3
  const int wk   = w & 1;              // 64-col stripe within 128-col region
  const int kh   = w >> 1;             // k-half 0/1
  const int lane = tid & 63;
  const int q4   = lane >> 4;          // MFMA k-octet
  const int cl   = lane & 15;          // MFMA col-in-frag
  const int ww   = lane & 3;           // dequant: word -> cols 8ww..8ww+7
  const int kp2  = lane >> 2;          // dequant: k-pair 0..15
  const int kps  = kp2 ^ (ww << 2);    // swizzled k-pair slot (verified)

  // Bijective XCD swizzle (688 = 8*86)
  const int b  = blockIdx.x;
  const int L  = (b & 7) * (NBLK / 8) + (b >> 3);
  const int colb = L % NCOLB;
  const int kc   = L / NCOLB;          // slab k-region 0..7

  const int kchunk = kc * 2 + kh;      // 0..15
  const int cb  = colb * 128;          // first output column of region
  const int wcb = colb * 16;           // first packed word of region
  const int K0  = kchunk * CHUNK;
  const int g0  = kchunk * (CHUNK / 128);   // 2 groups per chunk
  const int cw  = cb + wk * 64;        // wave's first column
  const int wqw = wcb + wk * 8;        // wave's first packed word

  // group scale/zero per half: raw staging -> fp16 splat pairs
  f32x4 sra[2], srb[2]; int zrw[2];
  half2v nz[2][8], ss[2][8];
  auto load_group_raw = [&](int g) {
    #pragma unroll
    for (int h = 0; h < 2; ++h) {
      sra[h] = *(const f32x4*)(sc + g * OUT_F + cw + h * 32 + ww * 8);
      srb[h] = *(const f32x4*)(sc + g * OUT_F + cw + h * 32 + ww * 8 + 4);
      zrw[h] = qz[g * WCOLS + wqw + h * 4 + ww];
    }
  };
  auto conv_group = [&]() {
    #pragma unroll
    for (int h = 0; h < 2; ++h) {
      #pragma unroll
      for (int l = 0; l < 8; ++l) {
        const int sh = 4 * (l >> 1) + 16 * (l & 1);   // shift = 4*REV[l]
        const int zi = (zrw[h] >> sh) & 15;
        nz[h][l] = splat_h(-(float)(1024 + zi));
        ss[h][l] = splat_h((l < 4) ? sra[h][l] : srb[h][l - 4]);
      }
    }
  };
  auto load_a = [&](int t, int mf) -> half8v {
    const int m = cl + 16 * mf;
    if constexpr (TOWS) {
      // fragment-major xb2: one coalesced 16B/lane load (16 lines/instr)
      const int ko = (K0 >> 3) + t * 4 + q4;
      return *(const half8v*)(xb2 + (ko * 32 + m) * 8);
    } else {
      const int k = K0 + t * 32 + q4 * 8;
      const f32x4* xp = (const f32x4*)(x + m * IN_F + k);
      const f32x4 lo = xp[0], hi = xp[1];
      int4v wd;
      wd[0] = __builtin_bit_cast(int, __builtin_amdgcn_cvt_pkrtz(lo[0], lo[1]));
      wd[1] = __builtin_bit_cast(int, __builtin_amdgcn_cvt_pkrtz(lo[2], lo[3]));
      wd[2] = __builtin_bit_cast(int, __builtin_amdgcn_cvt_pkrtz(hi[0], hi[1]));
      wd[3] = __builtin_bit_cast(int, __builtin_amdgcn_cvt_pkrtz(hi[2], hi[3]));
      return __builtin_bit_cast(half8v, wd);
    }
  };
  // read col c, k=8q4..8q4+7: slot s=4(c&7)+(c>>3), quads at 4*(q4^(c>>3))
  // contiguous since (4q4+m)^(4w') = 4(q4^w')+m.
  auto read_b = [&](int p, int h, int c) -> half8v {
    const int s = ((c & 7) << 2) | (c >> 3);
    const int idx = s * 16 + 4 * (q4 ^ (c >> 3));
    return __builtin_bit_cast(half8v, *(const int4v*)&lds[p][w][h][idx]);
  };

  // ---- prologue: group-0 raws, ALL q-loads (8 tiles x 2 halves) to regs.
  load_group_raw(g0);
  int qa[NTILE][2], qb[NTILE][2];
  #pragma unroll
  for (int t = 0; t < NTILE; ++t) {
    #pragma unroll
    for (int h = 0; h < 2; ++h) {
      const int r = (K0 + t * 32 + 2 * kp2) * WCOLS + wqw + h * 4 + ww;
      qa[t][h] = qw[r];
      qb[t][h] = qw[r + WCOLS];
    }
  }
  conv_group();
  f32x4 acc[2][2][2] = {};   // [mf][h][cfrag]

  // fp16 perm-dequant + LDS-write for tile t. Store col c=8ww+l at slot
  // l*4+ww (bank = 16(ww&1)+kps -> 2-way, free), quad kps.
  auto dq_write = [&](int t) {
    const int p = t & 1;
    #pragma unroll
    for (int h = 0; h < 2; ++h) {
      const int q0 = qa[t][h], q1 = qb[t][h];
      const int h0 = (int)((unsigned)q0 >> 4);
      const int h1 = (int)((unsigned)q1 >> 4);
      #pragma unroll
      for (int l = 0; l < 8; ++l) {
        const int pb = 2 * (l & 1) + (l >> 2);             // source byte
        const unsigned sel = (unsigned)(4 + pb) | ((unsigned)(4 + pb) << 8)
                           | ((unsigned)pb << 16) | ((unsigned)pb << 24);
        const int x0 = ((l >> 1) & 1) ? h0 : q0;
        const int x1 = ((l >> 1) & 1) ? h1 : q1;
        unsigned P = __builtin_amdgcn_perm((unsigned)x0, (unsigned)x1, sel);
        unsigned W = (P & 0x000F000Fu) | 0x64006400u;      // fp16: 1024+n
        half2v wh = (__builtin_bit_cast(half2v, W) + nz[h][l]) * ss[h][l];
        lds[p][w][h][(l * 4 + ww) * 16 + kps] = __builtin_bit_cast(int, wh);
      }
    }
  };

  // ---- pipelined main loop: write(t) while consuming (t-1)
  dq_write(0);
  half8v a0c = load_a(0, 0), a1c = load_a(0, 1);

  #pragma unroll
  for (int t = 1; t < NTILE; ++t) {
    const int pm = (t - 1) & 1;
    half8v bf00 = read_b(pm, 0, cl), bf01 = read_b(pm, 0, cl + 16);
    half8v bf10 = read_b(pm, 1, cl), bf11 = read_b(pm, 1, cl + 16);
    half8v a0n = load_a(t, 0), a1n = load_a(t, 1);
    if (t == 2) load_group_raw(g0 + 1);   // raws 2 tiles early
    if (t == 4) conv_group();             // group 1 live for tiles 4..7

    dq_write(t);                          // VALU hides the reads above

    acc[0][0][0] = mfma16h(a0c, bf00, acc[0][0][0]);
    acc[0][0][1] = mfma16h(a0c, bf01, acc[0][0][1]);
    acc[1][0][0] = mfma16h(a1c, bf00, acc[1][0][0]);
    acc[1][0][1] = mfma16h(a1c, bf01, acc[1][0][1]);
    acc[0][1][0] = mfma16h(a0c, bf10, acc[0][1][0]);
    acc[0][1][1] = mfma16h(a0c, bf11, acc[0][1][1]);
    acc[1][1][0] = mfma16h(a1c, bf10, acc[1][1][0]);
    acc[1][1][1] = mfma16h(a1c, bf11, acc[1][1][1]);

    a0c = a0n; a1c = a1n;
  }

  // ---- final tile (reads from lds[1] only: pm = 7&1 = 1)
  {
    const int pm = (NTILE - 1) & 1;
    half8v bf00 = read_b(pm, 0, cl), bf01 = read_b(pm, 0, cl + 16);
    half8v bf10 = read_b(pm, 1, cl), bf11 = read_b(pm, 1, cl + 16);
    acc[0][0][0] = mfma16h(a0c, bf00, acc[0][0][0]);
    acc[0][0][1] = mfma16h(a0c, bf01, acc[0][0][1]);
    acc[1][0][0] = mfma16h(a1c, bf00, acc[1][0][0]);
    acc[1][0][1] = mfma16h(a1c, bf01, acc[1][0][1]);
    acc[0][1][0] = mfma16h(a0c, bf10, acc[0][1][0]);
    acc[0][1][1] = mfma16h(a0c, bf11, acc[0][1][1]);
    acc[1][1][0] = mfma16h(a1c, bf10, acc[1][1][0]);
    acc[1][1][1] = mfma16h(a1c, bf11, acc[1][1][1]);
  }

  // ---- output epilogue
  const int r0 = q4 * 4;
  if constexpr (TOWS) {
    // in-block k-pair sum through lds[0] (idx-major: conflict-free,
    // no overlap with lds[1], which held the final tile)
    float* xch = (float*)&lds[0][0][0][0];   // 4096 floats = 16 KB
    const int base = wk * 64 + lane;         // 0..127
    __syncthreads();                         // all waves past main loop
    if (kh == 1) {
      #pragma unroll
      for (int mf = 0; mf < 2; ++mf)
        #pragma unroll
        for (int h = 0; h < 2; ++h)
          #pragma unroll
          for (int cf = 0; cf < 2; ++cf)
            #pragma unroll
            for (int i = 0; i < 4; ++i) {
              const int e = (((mf * 2 + h) * 2 + cf) * 4 + i);
              xch[e * 128 + base] = acc[mf][h][cf][i];
            }
    }
    __syncthreads();
    if (kh == 0) {
      unsigned short* wsp = (unsigned short*)outp + kc * SLAB;
      #pragma unroll
      for (int mf = 0; mf < 2; ++mf)
        #pragma unroll
        for (int h = 0; h < 2; ++h)
          #pragma unroll
          for (int cf = 0; cf < 2; ++cf)
            #pragma unroll
            for (int i = 0; i < 4; ++i) {
              const int e = (((mf * 2 + h) * 2 + cf) * 4 + i);
              const float sum = acc[mf][h][cf][i] + xch[e * 128 + base];
              const int row = mf * 16 + r0 + i;
              const int c0  = cw + h * 32 + cl + cf * 16;
              __builtin_nontemporal_store(f2bfu(sum), wsp + row * OUT_F + c0);
            }
    }
  } else {
    // fallback: fp32 atomics onto bias-initialized out
    float* op = (float*)outp;
    #pragma unroll
    for (int mf = 0; mf < 2; ++mf) {
      #pragma unroll
      for (int h = 0; h < 2; ++h) {
        #pragma unroll
        for (int i = 0; i < 4; ++i) {
          const int row = mf * 16 + r0 + i;
          const int c0  = cw + h * 32 + cl;
          atomicAdd(op + row * OUT_F + c0,      acc[mf][h][0][i]);
          atomicAdd(op + row * OUT_F + c0 + 16, acc[mf][h][1][i]);
        }
      }
    }
  }
}

extern "C" void kernel_launch(void* const* d_in, const int* in_sizes, int n_in,
                              void* d_out, int out_size, void* d_ws, size_t ws_size,
                              hipStream_t stream) {
  const float* x    = (const float*)d_in[0];
  const int*   qwp  = (const int*)d_in[1];
  const int*   qzp  = (const int*)d_in[2];
  const float* scp  = (const float*)d_in[3];
  const float* bias = (const float*)d_in[4];
  float* out = (float*)d_out;

  const size_t ws_slabs = (size_t)NKC * SLAB * 2;     // 5.6 MB (bf16)
  const size_t xb_sz    = (size_t)MROWS * IN_F * 2;   // 256 KB

  if (ws_size >= ws_slabs + xb_sz) {
    unsigned short* ws = (unsigned short*)d_ws;
    _Float16* xb2 = (_Float16*)((char*)d_ws + ws_slabs);
    xconv2<<<64, 256, 0, stream>>>(x, xb2);
    awq_main<true><<<NBLK, 256, 0, stream>>>(x, xb2, qwp, qzp, scp, ws);
    awq_reduce<<<SLAB / 4 / 256, 256, 0, stream>>>(ws, bias, out);
  } else {
    awq_init<<<dim3(43, 32), 256, 0, stream>>>(bias, out);
    awq_main<false><<<NBLK, 256, 0, stream>>>(x, nullptr, qwp, qzp, scp, out);
  }
}

// Round 26
// 21.289 us; speedup vs baseline: 1.2138x; 1.1302x over previous
//
#include <hip/hip_runtime.h>
#include <hip/hip_bf16.h>

// AWQ 4-bit linear: out[32,11008] = x[32,4096] @ ((q - z)*s) + bias
// Round 26: TWO-KERNEL pipeline. xconv2 eliminated: each block stages its
// kchunk's A-slice (32m x 256k fp16, 16KB) into LDS in the prologue
// (coalesced x loads + cvt_pkrtz + one barrier = the q-hoist's drain-once
// point); in-loop a-loads become ds_read_b128 (zero TA lookups). Geometry
// reverted to R18's 256col x 1kchunk blocks (R21 pair-sum was neutral) ->
// LDS 32+16 = 48KB, still 3 blocks/CU. fp16 perm-dequant, rotated-slot
// LDS, q-hoist, software pipeline, 16 bf16 nt-slabs + reduce: unchanged.

#define IN_F   4096
#define OUT_F  11008
#define WCOLS  1376
#define NCOLB  43                 // 256-col regions
#define KSPLIT 16
#define CHUNK  (IN_F/KSPLIT)      // 256
#define NTILE  (CHUNK/32)         // 8
#define NBLK   (NCOLB*KSPLIT)     // 688 = 8*86
#define MROWS  32
#define SLAB   (MROWS*OUT_F)      // elements per k-partial slab (352256)

typedef __attribute__((ext_vector_type(2))) _Float16 half2v;
typedef __attribute__((ext_vector_type(8))) _Float16 half8v;
typedef __attribute__((ext_vector_type(4))) unsigned short ushort4v;
typedef __attribute__((ext_vector_type(4))) float  f32x4;
typedef __attribute__((ext_vector_type(4))) int    int4v;

__device__ __forceinline__ unsigned short f2bfu(float f) {
  return __builtin_bit_cast(unsigned short, (__bf16)f);
}
__device__ __forceinline__ float bf2f(unsigned short u) {
  return __builtin_bit_cast(float, ((unsigned int)u) << 16);
}
__device__ __forceinline__ half2v splat_h(float f) {
  unsigned short b = __builtin_bit_cast(unsigned short, (_Float16)f);
  unsigned int u = (unsigned int)b | ((unsigned int)b << 16);
  return __builtin_bit_cast(half2v, u);
}
__device__ __forceinline__ f32x4 mfma16h(half8v a, half8v b, f32x4 c) {
  return __builtin_amdgcn_mfma_f32_16x16x32_f16(a, b, c, 0, 0, 0);
}

__global__ void awq_init(const float* __restrict__ bias, float* __restrict__ out) {
  int o = blockIdx.x * 256 + threadIdx.x;
  out[blockIdx.y * OUT_F + o] = bias[o];
}

__global__ __launch_bounds__(256) void awq_reduce(
    const unsigned short* __restrict__ ws, const float* __restrict__ bias,
    float* __restrict__ out)
{
  const int i = blockIdx.x * 256 + threadIdx.x;    // 4-col id, 88064 total
  f32x4 s = *(const f32x4*)(bias + (i % (OUT_F / 4)) * 4);
  const ushort4v* w4 = (const ushort4v*)ws;
  #pragma unroll
  for (int k = 0; k < KSPLIT; ++k) {
    ushort4v v = __builtin_nontemporal_load(&w4[k * (SLAB / 4) + i]);
    #pragma unroll
    for (int j = 0; j < 4; ++j) s[j] += bf2f(v[j]);
  }
  ((f32x4*)out)[i] = s;
}

template<bool TOWS>
__global__ __launch_bounds__(256, 3) void awq_main(
    const float* __restrict__ x,
    const int* __restrict__ qw, const int* __restrict__ qz,
    const float* __restrict__ sc, void* __restrict__ outp)
{
  // Staging: [buf][wave][half][512 dw] = 32 KB; A-slice xa = 16 KB.
  __shared__ int lds[2][4][2][512];
  __shared__ int4v xa[1024];           // [ko 0..31][m 0..31] fp16x8

  const int tid  = threadIdx.x;
  const int w    = tid >> 6;           // wave 0..3 -> 64-col stripe
  const int lane = tid & 63;
  const int q4   = lane >> 4;          // MFMA k-octet
  const int cl   = lane & 15;          // MFMA col-in-frag
  const int ww   = lane & 3;           // dequant: word -> cols 8ww..8ww+7
  const int kp2  = lane >> 2;          // dequant: k-pair 0..15
  const int kps  = kp2 ^ (ww << 2);    // swizzled k-pair slot (verified)

  // Bijective XCD swizzle (688 = 8*86)
  const int b  = blockIdx.x;
  const int L  = (b & 7) * (NBLK / 8) + (b >> 3);
  const int colb   = L % NCOLB;
  const int kchunk = L / NCOLB;

  const int cb  = colb * 256;          // first output column of region
  const int wcb = colb * 32;           // first packed word of region
  const int K0  = kchunk * CHUNK;
  const int g0  = kchunk * (CHUNK / 128);   // 2 groups per chunk
  const int cw  = cb + w * 64;         // wave's first column
  const int wqw = wcb + w * 8;         // wave's first packed word

  // group scale/zero per half: raw staging -> fp16 splat pairs
  f32x4 sra[2], srb[2]; int zrw[2];
  half2v nz[2][8], ss[2][8];
  auto load_group_raw = [&](int g) {
    #pragma unroll
    for (int h = 0; h < 2; ++h) {
      sra[h] = *(const f32x4*)(sc + g * OUT_F + cw + h * 32 + ww * 8);
      srb[h] = *(const f32x4*)(sc + g * OUT_F + cw + h * 32 + ww * 8 + 4);
      zrw[h] = qz[g * WCOLS + wqw + h * 4 + ww];
    }
  };
  auto conv_group = [&]() {
    #pragma unroll
    for (int h = 0; h < 2; ++h) {
      #pragma unroll
      for (int l = 0; l < 8; ++l) {
        const int sh = 4 * (l >> 1) + 16 * (l & 1);   // shift = 4*REV[l]
        const int zi = (zrw[h] >> sh) & 15;
        nz[h][l] = splat_h(-(float)(1024 + zi));
        ss[h][l] = splat_h((l < 4) ? sra[h][l] : srb[h][l - 4]);
      }
    }
  };
  auto load_a = [&](int t, int mf) -> half8v {
    const int m = cl + 16 * mf;
    if constexpr (TOWS) {
      return __builtin_bit_cast(half8v, xa[(t * 4 + q4) * 32 + m]);
    } else {
      const int k = K0 + t * 32 + q4 * 8;
      const f32x4* xp = (const f32x4*)(x + m * IN_F + k);
      const f32x4 lo = xp[0], hi = xp[1];
      int4v wd;
      wd[0] = __builtin_bit_cast(int, __builtin_amdgcn_cvt_pkrtz(lo[0], lo[1]));
      wd[1] = __builtin_bit_cast(int, __builtin_amdgcn_cvt_pkrtz(lo[2], lo[3]));
      wd[2] = __builtin_bit_cast(int, __builtin_amdgcn_cvt_pkrtz(hi[0], hi[1]));
      wd[3] = __builtin_bit_cast(int, __builtin_amdgcn_cvt_pkrtz(hi[2], hi[3]));
      return __builtin_bit_cast(half8v, wd);
    }
  };
  // read col c, k=8q4..8q4+7: slot s=4(c&7)+(c>>3), quads at 4*(q4^(c>>3))
  auto read_b = [&](int p, int h, int c) -> half8v {
    const int s = ((c & 7) << 2) | (c >> 3);
    const int idx = s * 16 + 4 * (q4 ^ (c >> 3));
    return __builtin_bit_cast(half8v, *(const int4v*)&lds[p][w][h][idx]);
  };

  // ---- prologue: group-0 raws, ALL q-loads (8 tiles x 2 halves) to regs,
  // then cooperative A-slice staging (x -> fp16 LDS) + one barrier.
  load_group_raw(g0);
  int qa[NTILE][2], qb[NTILE][2];
  #pragma unroll
  for (int t = 0; t < NTILE; ++t) {
    #pragma unroll
    for (int h = 0; h < 2; ++h) {
      const int r = (K0 + t * 32 + 2 * kp2) * WCOLS + wqw + h * 4 + ww;
      qa[t][h] = qw[r];
      qb[t][h] = qw[r + WCOLS];
    }
  }
  if constexpr (TOWS) {
    const int mrow = tid >> 3;          // 0..31
    const int kc8  = tid & 7;           // 0..7
    #pragma unroll
    for (int r = 0; r < 4; ++r) {
      const int k0l = r * 64 + kc8 * 8; // local k, step 8
      const f32x4* xp = (const f32x4*)(x + mrow * IN_F + K0 + k0l);
      const f32x4 lo = xp[0], hi = xp[1];
      int4v wd;
      wd[0] = __builtin_bit_cast(int, __builtin_amdgcn_cvt_pkrtz(lo[0], lo[1]));
      wd[1] = __builtin_bit_cast(int, __builtin_amdgcn_cvt_pkrtz(lo[2], lo[3]));
      wd[2] = __builtin_bit_cast(int, __builtin_amdgcn_cvt_pkrtz(hi[0], hi[1]));
      wd[3] = __builtin_bit_cast(int, __builtin_amdgcn_cvt_pkrtz(hi[2], hi[3]));
      xa[(k0l >> 3) * 32 + mrow] = wd;
    }
    __syncthreads();                    // xa ready; also drains q-hoist once
  }
  conv_group();
  f32x4 acc[2][2][2] = {};   // [mf][h][cfrag]

  // fp16 perm-dequant + LDS-write for tile t (store col c=8ww+l at slot
  // l*4+ww, quad kps).
  auto dq_write = [&](int t) {
    const int p = t & 1;
    #pragma unroll
    for (int h = 0; h < 2; ++h) {
      const int q0 = qa[t][h], q1 = qb[t][h];
      const int h0 = (int)((unsigned)q0 >> 4);
      const int h1 = (int)((unsigned)q1 >> 4);
      #pragma unroll
      for (int l = 0; l < 8; ++l) {
        const int pb = 2 * (l & 1) + (l >> 2);             // source byte
        const unsigned sel = (unsigned)(4 + pb) | ((unsigned)(4 + pb) << 8)
                           | ((unsigned)pb << 16) | ((unsigned)pb << 24);
        const int x0 = ((l >> 1) & 1) ? h0 : q0;
        const int x1 = ((l >> 1) & 1) ? h1 : q1;
        unsigned P = __builtin_amdgcn_perm((unsigned)x0, (unsigned)x1, sel);
        unsigned W = (P & 0x000F000Fu) | 0x64006400u;      // fp16: 1024+n
        half2v wh = (__builtin_bit_cast(half2v, W) + nz[h][l]) * ss[h][l];
        lds[p][w][h][(l * 4 + ww) * 16 + kps] = __builtin_bit_cast(int, wh);
      }
    }
  };

  // ---- pipelined main loop: write(t) while consuming (t-1)
  dq_write(0);
  half8v a0c = load_a(0, 0), a1c = load_a(0, 1);

  #pragma unroll
  for (int t = 1; t < NTILE; ++t) {
    const int pm = (t - 1) & 1;
    half8v bf00 = read_b(pm, 0, cl), bf01 = read_b(pm, 0, cl + 16);
    half8v bf10 = read_b(pm, 1, cl), bf11 = read_b(pm, 1, cl + 16);
    half8v a0n = load_a(t, 0), a1n = load_a(t, 1);
    if (t == 2) load_group_raw(g0 + 1);   // raws 2 tiles early
    if (t == 4) conv_group();             // group 1 live for tiles 4..7

    dq_write(t);                          // VALU hides the reads above

    acc[0][0][0] = mfma16h(a0c, bf00, acc[0][0][0]);
    acc[0][0][1] = mfma16h(a0c, bf01, acc[0][0][1]);
    acc[1][0][0] = mfma16h(a1c, bf00, acc[1][0][0]);
    acc[1][0][1] = mfma16h(a1c, bf01, acc[1][0][1]);
    acc[0][1][0] = mfma16h(a0c, bf10, acc[0][1][0]);
    acc[0][1][1] = mfma16h(a0c, bf11, acc[0][1][1]);
    acc[1][1][0] = mfma16h(a1c, bf10, acc[1][1][0]);
    acc[1][1][1] = mfma16h(a1c, bf11, acc[1][1][1]);

    a0c = a0n; a1c = a1n;
  }

  // ---- final tile (reads from lds[1] only: pm = 7&1 = 1)
  {
    const int pm = (NTILE - 1) & 1;
    half8v bf00 = read_b(pm, 0, cl), bf01 = read_b(pm, 0, cl + 16);
    half8v bf10 = read_b(pm, 1, cl), bf11 = read_b(pm, 1, cl + 16);
    acc[0][0][0] = mfma16h(a0c, bf00, acc[0][0][0]);
    acc[0][0][1] = mfma16h(a0c, bf01, acc[0][0][1]);
    acc[1][0][0] = mfma16h(a1c, bf00, acc[1][0][0]);
    acc[1][0][1] = mfma16h(a1c, bf01, acc[1][0][1]);
    acc[0][1][0] = mfma16h(a0c, bf10, acc[0][1][0]);
    acc[0][1][1] = mfma16h(a0c, bf11, acc[0][1][1]);
    acc[1][1][0] = mfma16h(a1c, bf10, acc[1][1][0]);
    acc[1][1][1] = mfma16h(a1c, bf11, acc[1][1][1]);
  }

  // ---- output epilogue
  const int r0 = q4 * 4;
  if constexpr (TOWS) {
    // bf16 partials, non-temporal (write-once-read-once; skip L2)
    unsigned short* wsp = (unsigned short*)outp + kchunk * SLAB;
    #pragma unroll
    for (int mf = 0; mf < 2; ++mf) {
      #pragma unroll
      for (int h = 0; h < 2; ++h) {
        #pragma unroll
        for (int i = 0; i < 4; ++i) {
          const int row = mf * 16 + r0 + i;
          const int c0  = cw + h * 32 + cl;
          __builtin_nontemporal_store(f2bfu(acc[mf][h][0][i]),
                                      wsp + row * OUT_F + c0);
          __builtin_nontemporal_store(f2bfu(acc[mf][h][1][i]),
                                      wsp + row * OUT_F + c0 + 16);
        }
      }
    }
  } else {
    // fallback: fp32 atomics onto bias-initialized out
    float* op = (float*)outp;
    #pragma unroll
    for (int mf = 0; mf < 2; ++mf) {
      #pragma unroll
      for (int h = 0; h < 2; ++h) {
        #pragma unroll
        for (int i = 0; i < 4; ++i) {
          const int row = mf * 16 + r0 + i;
          const int c0  = cw + h * 32 + cl;
          atomicAdd(op + row * OUT_F + c0,      acc[mf][h][0][i]);
          atomicAdd(op + row * OUT_F + c0 + 16, acc[mf][h][1][i]);
        }
      }
    }
  }
}

extern "C" void kernel_launch(void* const* d_in, const int* in_sizes, int n_in,
                              void* d_out, int out_size, void* d_ws, size_t ws_size,
                              hipStream_t stream) {
  const float* x    = (const float*)d_in[0];
  const int*   qwp  = (const int*)d_in[1];
  const int*   qzp  = (const int*)d_in[2];
  const float* scp  = (const float*)d_in[3];
  const float* bias = (const float*)d_in[4];
  float* out = (float*)d_out;

  const size_t ws_slabs = (size_t)KSPLIT * SLAB * 2;   // 11.25 MB (bf16)

  if (ws_size >= ws_slabs) {
    unsigned short* ws = (unsigned short*)d_ws;
    awq_main<true><<<NBLK, 256, 0, stream>>>(x, qwp, qzp, scp, ws);
    awq_reduce<<<SLAB / 4 / 256, 256, 0, stream>>>(ws, bias, out);
  } else {
    awq_init<<<dim3(43, 32), 256, 0, stream>>>(bias, out);
    awq_main<false><<<NBLK, 256, 0, stream>>>(x, qwp, qzp, scp, out);
  }
}

// Round 27
// 21.103 us; speedup vs baseline: 1.2245x; 1.0088x over previous
//
#include <hip/hip_runtime.h>
#include <hip/hip_bf16.h>

// AWQ 4-bit linear: out[32,11008] = x[32,4096] @ ((q - z)*s) + bias
// Round 27: Q-LOOKUP HALVING on the R26 winner (21.3us). Lane word-pair
// re-mapped from {wqw+ww, wqw+4+ww} (16B apart -> 2 scalar loads) to
// adjacent {2ww, 2ww+1} -> ONE dwordx2 per row: q-load instrs 4->2/tile,
// rows/instr unchanged but 32B contiguous -> TA lookups 64->32/tile
// (512->256/wave, the dominant remaining TA term). Zeros pair into one
// dwordx2. LDS write uses the generalized verified rule: col c -> slot
// 4(c&7)+(cl>>3), k-pair kp2^4(cl>>3); READ SIDE BYTE-IDENTICAL.
// A-staging in LDS, fp16 perm-dequant, software pipeline, 16 bf16
// nt-slabs + reduce: unchanged from R26.

#define IN_F   4096
#define OUT_F  11008
#define WCOLS  1376
#define NCOLB  43                 // 256-col regions
#define KSPLIT 16
#define CHUNK  (IN_F/KSPLIT)      // 256
#define NTILE  (CHUNK/32)         // 8
#define NBLK   (NCOLB*KSPLIT)     // 688 = 8*86
#define MROWS  32
#define SLAB   (MROWS*OUT_F)      // elements per k-partial slab (352256)

typedef __attribute__((ext_vector_type(2))) _Float16 half2v;
typedef __attribute__((ext_vector_type(8))) _Float16 half8v;
typedef __attribute__((ext_vector_type(4))) unsigned short ushort4v;
typedef __attribute__((ext_vector_type(4))) float  f32x4;
typedef __attribute__((ext_vector_type(2))) int    int2v;
typedef __attribute__((ext_vector_type(4))) int    int4v;

__device__ __forceinline__ unsigned short f2bfu(float f) {
  return __builtin_bit_cast(unsigned short, (__bf16)f);
}
__device__ __forceinline__ float bf2f(unsigned short u) {
  return __builtin_bit_cast(float, ((unsigned int)u) << 16);
}
__device__ __forceinline__ half2v splat_h(float f) {
  unsigned short b = __builtin_bit_cast(unsigned short, (_Float16)f);
  unsigned int u = (unsigned int)b | ((unsigned int)b << 16);
  return __builtin_bit_cast(half2v, u);
}
__device__ __forceinline__ f32x4 mfma16h(half8v a, half8v b, f32x4 c) {
  return __builtin_amdgcn_mfma_f32_16x16x32_f16(a, b, c, 0, 0, 0);
}

__global__ void awq_init(const float* __restrict__ bias, float* __restrict__ out) {
  int o = blockIdx.x * 256 + threadIdx.x;
  out[blockIdx.y * OUT_F + o] = bias[o];
}

__global__ __launch_bounds__(256) void awq_reduce(
    const unsigned short* __restrict__ ws, const float* __restrict__ bias,
    float* __restrict__ out)
{
  const int i = blockIdx.x * 256 + threadIdx.x;    // 4-col id, 88064 total
  f32x4 s = *(const f32x4*)(bias + (i % (OUT_F / 4)) * 4);
  const ushort4v* w4 = (const ushort4v*)ws;
  #pragma unroll
  for (int k = 0; k < KSPLIT; ++k) {
    ushort4v v = __builtin_nontemporal_load(&w4[k * (SLAB / 4) + i]);
    #pragma unroll
    for (int j = 0; j < 4; ++j) s[j] += bf2f(v[j]);
  }
  ((f32x4*)out)[i] = s;
}

template<bool TOWS>
__global__ __launch_bounds__(256, 3) void awq_main(
    const float* __restrict__ x,
    const int* __restrict__ qw, const int* __restrict__ qz,
    const float* __restrict__ sc, void* __restrict__ outp)
{
  // Staging: [buf][wave][half][512 dw] = 32 KB; A-slice xa = 16 KB.
  __shared__ int lds[2][4][2][512];
  __shared__ int4v xa[1024];           // [ko 0..31][m 0..31] fp16x8

  const int tid  = threadIdx.x;
  const int w    = tid >> 6;           // wave 0..3 -> 64-col stripe
  const int lane = tid & 63;
  const int q4   = lane >> 4;          // MFMA k-octet
  const int cl   = lane & 15;          // MFMA col-in-frag
  const int ww   = lane & 3;           // dequant: word-PAIR 2ww,2ww+1
  const int kp2  = lane >> 2;          // dequant: k-pair 0..15

  // Bijective XCD swizzle (688 = 8*86)
  const int b  = blockIdx.x;
  const int L  = (b & 7) * (NBLK / 8) + (b >> 3);
  const int colb   = L % NCOLB;
  const int kchunk = L / NCOLB;

  const int cb  = colb * 256;          // first output column of region
  const int wcb = colb * 32;           // first packed word of region
  const int K0  = kchunk * CHUNK;
  const int g0  = kchunk * (CHUNK / 128);   // 2 groups per chunk
  const int cw  = cb + w * 64;         // wave's first column
  const int wq2 = wcb + w * 8 + 2 * ww;     // lane's word-pair base

  // group scale/zero: raw staging -> fp16 splat pairs for 16 cols
  f32x4 sraw[4]; int2v zr;
  half2v nz[2][8], ss[2][8];
  auto load_group_raw = [&](int g) {
    const float* sp = sc + g * OUT_F + cw + 16 * ww;
    sraw[0] = *(const f32x4*)(sp);
    sraw[1] = *(const f32x4*)(sp + 4);
    sraw[2] = *(const f32x4*)(sp + 8);
    sraw[3] = *(const f32x4*)(sp + 12);
    zr = *(const int2v*)(qz + g * WCOLS + wq2);
  };
  auto conv_group = [&]() {
    #pragma unroll
    for (int wh = 0; wh < 2; ++wh) {
      #pragma unroll
      for (int l = 0; l < 8; ++l) {
        const int sh = 4 * (l >> 1) + 16 * (l & 1);   // shift = 4*REV[l]
        const int zi = (zr[wh] >> sh) & 15;
        nz[wh][l] = splat_h(-(float)(1024 + zi));
        ss[wh][l] = splat_h(sraw[2 * wh + (l >> 2)][l & 3]);
      }
    }
  };
  auto load_a = [&](int t, int mf) -> half8v {
    const int m = cl + 16 * mf;
    if constexpr (TOWS) {
      return __builtin_bit_cast(half8v, xa[(t * 4 + q4) * 32 + m]);
    } else {
      const int k = K0 + t * 32 + q4 * 8;
      const f32x4* xp = (const f32x4*)(x + m * IN_F + k);
      const f32x4 lo = xp[0], hi = xp[1];
      int4v wd;
      wd[0] = __builtin_bit_cast(int, __builtin_amdgcn_cvt_pkrtz(lo[0], lo[1]));
      wd[1] = __builtin_bit_cast(int, __builtin_amdgcn_cvt_pkrtz(lo[2], lo[3]));
      wd[2] = __builtin_bit_cast(int, __builtin_amdgcn_cvt_pkrtz(hi[0], hi[1]));
      wd[3] = __builtin_bit_cast(int, __builtin_amdgcn_cvt_pkrtz(hi[2], hi[3]));
      return __builtin_bit_cast(half8v, wd);
    }
  };
  // read col c (0..31 within half), k=8q4..8q4+7: slot 4(c&7)+(c>>3),
  // quad 4*(q4^(c>>3)) -- BYTE-IDENTICAL to R23-R26 verified read.
  auto read_b = [&](int p, int h, int c) -> half8v {
    const int s = ((c & 7) << 2) | (c >> 3);
    const int idx = s * 16 + 4 * (q4 ^ (c >> 3));
    return __builtin_bit_cast(half8v, *(const int4v*)&lds[p][w][h][idx]);
  };

  // ---- prologue: group-0 raws, ALL q-loads (8 tiles x dwordx2 pairs),
  // then cooperative A-slice staging + one barrier.
  load_group_raw(g0);
  int2v qa2[NTILE], qb2[NTILE];
  #pragma unroll
  for (int t = 0; t < NTILE; ++t) {
    const int r = (K0 + t * 32 + 2 * kp2) * WCOLS + wq2;
    qa2[t] = *(const int2v*)(qw + r);           // row 2kp2, words 2ww..2ww+1
    qb2[t] = *(const int2v*)(qw + r + WCOLS);   // row 2kp2+1
  }
  if constexpr (TOWS) {
    const int mrow = tid >> 3;          // 0..31
    const int kc8  = tid & 7;           // 0..7
    #pragma unroll
    for (int r = 0; r < 4; ++r) {
      const int k0l = r * 64 + kc8 * 8; // local k, step 8
      const f32x4* xp = (const f32x4*)(x + mrow * IN_F + K0 + k0l);
      const f32x4 lo = xp[0], hi = xp[1];
      int4v wd;
      wd[0] = __builtin_bit_cast(int, __builtin_amdgcn_cvt_pkrtz(lo[0], lo[1]));
      wd[1] = __builtin_bit_cast(int, __builtin_amdgcn_cvt_pkrtz(lo[2], lo[3]));
      wd[2] = __builtin_bit_cast(int, __builtin_amdgcn_cvt_pkrtz(hi[0], hi[1]));
      wd[3] = __builtin_bit_cast(int, __builtin_amdgcn_cvt_pkrtz(hi[2], hi[3]));
      xa[(k0l >> 3) * 32 + mrow] = wd;
    }
    __syncthreads();                    // xa ready; also drains q-hoist once
  }
  conv_group();
  f32x4 acc[2][2][2] = {};   // [mf][h][cfrag]

  // fp16 perm-dequant + LDS-write for tile t. Lane covers cols
  // c = 16ww + 8wh + l; c_loc = c&31, half-buf = ww>>1.
  // Write: slot 4l + wcl (wcl = (2ww+wh)&3), k-pair kp2 ^ (wcl<<2).
  auto dq_write = [&](int t) {
    const int p  = t & 1;
    const int hb = ww >> 1;
    #pragma unroll
    for (int wh = 0; wh < 2; ++wh) {
      const int q0 = qa2[t][wh], q1 = qb2[t][wh];
      const int h0 = (int)((unsigned)q0 >> 4);
      const int h1 = (int)((unsigned)q1 >> 4);
      const int wcl = (2 * ww + wh) & 3;
      const int kq  = kp2 ^ (wcl << 2);
      #pragma unroll
      for (int l = 0; l < 8; ++l) {
        const int pb = 2 * (l & 1) + (l >> 2);             // source byte
        const unsigned sel = (unsigned)(4 + pb) | ((unsigned)(4 + pb) << 8)
                           | ((unsigned)pb << 16) | ((unsigned)pb << 24);
        const int x0 = ((l >> 1) & 1) ? h0 : q0;
        const int x1 = ((l >> 1) & 1) ? h1 : q1;
        unsigned P = __builtin_amdgcn_perm((unsigned)x0, (unsigned)x1, sel);
        unsigned W = (P & 0x000F000Fu) | 0x64006400u;      // fp16: 1024+n
        half2v v = (__builtin_bit_cast(half2v, W) + nz[wh][l]) * ss[wh][l];
        lds[p][w][hb][(l * 4 + wcl) * 16 + kq] = __builtin_bit_cast(int, v);
      }
    }
  };

  // ---- pipelined main loop: write(t) while consuming (t-1)
  dq_write(0);
  half8v a0c = load_a(0, 0), a1c = load_a(0, 1);

  #pragma unroll
  for (int t = 1; t < NTILE; ++t) {
    const int pm = (t - 1) & 1;
    half8v bf00 = read_b(pm, 0, cl), bf01 = read_b(pm, 0, cl + 16);
    half8v bf10 = read_b(pm, 1, cl), bf11 = read_b(pm, 1, cl + 16);
    half8v a0n = load_a(t, 0), a1n = load_a(t, 1);
    if (t == 2) load_group_raw(g0 + 1);   // raws 2 tiles early
    if (t == 4) conv_group();             // group 1 live for tiles 4..7

    dq_write(t);                          // VALU hides the reads above

    acc[0][0][0] = mfma16h(a0c, bf00, acc[0][0][0]);
    acc[0][0][1] = mfma16h(a0c, bf01, acc[0][0][1]);
    acc[1][0][0] = mfma16h(a1c, bf00, acc[1][0][0]);
    acc[1][0][1] = mfma16h(a1c, bf01, acc[1][0][1]);
    acc[0][1][0] = mfma16h(a0c, bf10, acc[0][1][0]);
    acc[0][1][1] = mfma16h(a0c, bf11, acc[0][1][1]);
    acc[1][1][0] = mfma16h(a1c, bf10, acc[1][1][0]);
    acc[1][1][1] = mfma16h(a1c, bf11, acc[1][1][1]);

    a0c = a0n; a1c = a1n;
  }

  // ---- final tile (reads from lds[1] only: pm = 7&1 = 1)
  {
    const int pm = (NTILE - 1) & 1;
    half8v bf00 = read_b(pm, 0, cl), bf01 = read_b(pm, 0, cl + 16);
    half8v bf10 = read_b(pm, 1, cl), bf11 = read_b(pm, 1, cl + 16);
    acc[0][0][0] = mfma16h(a0c, bf00, acc[0][0][0]);
    acc[0][0][1] = mfma16h(a0c, bf01, acc[0][0][1]);
    acc[1][0][0] = mfma16h(a1c, bf00, acc[1][0][0]);
    acc[1][0][1] = mfma16h(a1c, bf01, acc[1][0][1]);
    acc[0][1][0] = mfma16h(a0c, bf10, acc[0][1][0]);
    acc[0][1][1] = mfma16h(a0c, bf11, acc[0][1][1]);
    acc[1][1][0] = mfma16h(a1c, bf10, acc[1][1][0]);
    acc[1][1][1] = mfma16h(a1c, bf11, acc[1][1][1]);
  }

  // ---- output epilogue
  const int r0 = q4 * 4;
  if constexpr (TOWS) {
    // bf16 partials, non-temporal (write-once-read-once; skip L2)
    unsigned short* wsp = (unsigned short*)outp + kchunk * SLAB;
    #pragma unroll
    for (int mf = 0; mf < 2; ++mf) {
      #pragma unroll
      for (int h = 0; h < 2; ++h) {
        #pragma unroll
        for (int i = 0; i < 4; ++i) {
          const int row = mf * 16 + r0 + i;
          const int c0  = cw + h * 32 + cl;
          __builtin_nontemporal_store(f2bfu(acc[mf][h][0][i]),
                                      wsp + row * OUT_F + c0);
          __builtin_nontemporal_store(f2bfu(acc[mf][h][1][i]),
                                      wsp + row * OUT_F + c0 + 16);
        }
      }
    }
  } else {
    // fallback: fp32 atomics onto bias-initialized out
    float* op = (float*)outp;
    #pragma unroll
    for (int mf = 0; mf < 2; ++mf) {
      #pragma unroll
      for (int h = 0; h < 2; ++h) {
        #pragma unroll
        for (int i = 0; i < 4; ++i) {
          const int row = mf * 16 + r0 + i;
          const int c0  = cw + h * 32 + cl;
          atomicAdd(op + row * OUT_F + c0,      acc[mf][h][0][i]);
          atomicAdd(op + row * OUT_F + c0 + 16, acc[mf][h][1][i]);
        }
      }
    }
  }
}

extern "C" void kernel_launch(void* const* d_in, const int* in_sizes, int n_in,
                              void* d_out, int out_size, void* d_ws, size_t ws_size,
                              hipStream_t stream) {
  const float* x    = (const float*)d_in[0];
  const int*   qwp  = (const int*)d_in[1];
  const int*   qzp  = (const int*)d_in[2];
  const float* scp  = (const float*)d_in[3];
  const float* bias = (const float*)d_in[4];
  float* out = (float*)d_out;

  const size_t ws_slabs = (size_t)KSPLIT * SLAB * 2;   // 11.25 MB (bf16)

  if (ws_size >= ws_slabs) {
    unsigned short* ws = (unsigned short*)d_ws;
    awq_main<true><<<NBLK, 256, 0, stream>>>(x, qwp, qzp, scp, ws);
    awq_reduce<<<SLAB / 4 / 256, 256, 0, stream>>>(ws, bias, out);
  } else {
    awq_init<<<dim3(43, 32), 256, 0, stream>>>(bias, out);
    awq_main<false><<<NBLK, 256, 0, stream>>>(x, qwp, qzp, scp, out);
  }
}